// Round 12
// baseline (1481.022 us; speedup 1.0000x reference)
//
#include <hip/hip_runtime.h>

#define VV 100000
#define BB 2048
#define TT 200
#define GG 192   // 3*C
#define PP 514
#define RPB 4    // batch rows per block (mimn_rnn)
#define NBT 1563 // ceil(VV/64) build-table blocks in prep

typedef _Float16 half8 __attribute__((ext_vector_type(8)));
typedef float floatx4 __attribute__((ext_vector_type(4)));
#define MFMA16(a, b, c) __builtin_amdgcn_mfma_f32_16x16x32_f16((a), (b), (c), 0, 0, 0)

// LDS-only barrier: __syncthreads() lowers to s_waitcnt vmcnt(0) lgkmcnt(0)
// + s_barrier, which drains the in-flight GI prefetch loads every phase.
// All 4 phase barriers only publish LDS data -> lgkmcnt(0) suffices.
#define BARRIER_LDS() do { \
    __asm__ volatile("s_waitcnt lgkmcnt(0)" ::: "memory"); \
    __builtin_amdgcn_s_barrier(); } while (0)

__device__ __forceinline__ float fsigm(float x) { return 1.0f / (1.0f + __expf(-x)); }
__device__ __forceinline__ float ftanh(float x) {
    // 1 - 2/(e^{2x}+1): saturates correctly for |x| large (inf-safe)
    float e = __expf(2.0f * x);
    return 1.0f - 2.0f / (e + 1.0f);
}
__device__ __forceinline__ float fsoftplus(float x) {
    float e = __expf(-fabsf(x));
    return fmaxf(x, 0.0f) + __logf(1.0f + e);
}

// DPP wave64 sum: 6 v_add_f32_dpp + readlane, no LDS.
#define DPP_ADD(x, ctrl, rmask) \
    ((x) + __int_as_float(__builtin_amdgcn_update_dpp( \
        0, __float_as_int(x), (ctrl), (rmask), 0xf, true)))
__device__ __forceinline__ float wsum64(float x) {
    x = DPP_ADD(x, 0x111, 0xf);   // row_shr:1
    x = DPP_ADD(x, 0x112, 0xf);   // row_shr:2
    x = DPP_ADD(x, 0x114, 0xf);   // row_shr:4
    x = DPP_ADD(x, 0x118, 0xf);   // row_shr:8
    x = DPP_ADD(x, 0x142, 0xa);   // row_bcast:15 -> rows 1,3
    x = DPP_ADD(x, 0x143, 0xc);   // row_bcast:31 -> rows 2,3
    return __int_as_float(__builtin_amdgcn_readlane(__float_as_int(x), 63));
}
__device__ __forceinline__ float dot4(float4 w, float4 a) {
    return w.x * a.x + w.y * a.y + w.z * a.z + w.w * a.w;
}

// ---------------- K0: fused prep — MFMA table build + hist stats ----------------
// blocks [0, NBT): GI tables via f16 MFMA (f32 accum), 64 vocab rows/block.
// blocks [NBT, NBT+BB/2): hist_sum + seqlen, 2 batch rows per 256-thr block.
__global__ __launch_bounds__(256) void prep(
    const float* __restrict__ emb,   // V x 64
    const float* __restrict__ Wih,   // 192 x 256
    const float* __restrict__ bih,   // 192
    const int* __restrict__ hist_item, const int* __restrict__ hist_cate,
    const float* __restrict__ mask,
    float* __restrict__ GIi, float* __restrict__ GIc,  // V x 192 each
    float* __restrict__ hist_sum, int* __restrict__ seqlen)
{
    __shared__ __align__(16) _Float16 sE16[64 * 72];   // emb tile, padded rows
    const int tid = threadIdx.x;
    const int wv = tid >> 6, lane = tid & 63;
    const int nlo = lane & 15, kg = lane >> 4;

    if (blockIdx.x < NBT) {
        const int v0 = blockIdx.x * 64;
        // stage emb rows v0..v0+63 as f16 (zero-pad OOB vocab)
        for (int i = tid; i < 64 * 64; i += 256) {
            int vv = i >> 6, k = i & 63;
            int gv = v0 + vv;
            sE16[vv * 72 + k] = (gv < VV) ? (_Float16)emb[(size_t)gv * 64 + k]
                                          : (_Float16)0.f;
        }
        // weight fragments: wave wv owns pairs pid = 6*wv + j over
        // 24 = {item(12 n-tiles), cate(12 n-tiles)}; K=64 -> 2 half8 each
        half8 WF[6][2];
        float bias[6];
#pragma unroll
        for (int j = 0; j < 6; ++j) {
            int pid = 6 * wv + j;
            int tb = pid / 12, nt = pid % 12;
            int n = nt * 16 + nlo;
#pragma unroll
            for (int kb = 0; kb < 2; ++kb) {
                half8 f;
#pragma unroll
                for (int q = 0; q < 8; ++q)
                    f[q] = (_Float16)Wih[n * 256 + tb * 64 + kb * 32 + kg * 8 + q];
                WF[j][kb] = f;
            }
            bias[j] = tb ? 0.f : bih[n];
        }
        __syncthreads();
#pragma unroll
        for (int mt = 0; mt < 4; ++mt) {
            const int ar = (16 * mt + nlo) * 72 + 8 * kg;
            half8 a0 = *(const half8*)&sE16[ar];
            half8 a1 = *(const half8*)&sE16[ar + 32];
#pragma unroll
            for (int j = 0; j < 6; ++j) {
                floatx4 acc = {0.f, 0.f, 0.f, 0.f};
                acc = MFMA16(a0, WF[j][0], acc);
                acc = MFMA16(a1, WF[j][1], acc);
                int pid = 6 * wv + j;
                int tb = pid / 12, nt = pid % 12;
                float* dst = tb ? GIc : GIi;
                int n = nt * 16 + nlo;
#pragma unroll
                for (int q = 0; q < 4; ++q) {
                    int gv = v0 + 16 * mt + 4 * kg + q;
                    if (gv < VV) dst[(size_t)gv * GG + n] = acc[q] + bias[j];
                }
            }
        }
    } else {
        // hist path: 2 batch rows/block; waves {0,1}=row A (item/cate),
        // waves {2,3}=row B
        const int hb = blockIdx.x - NBT;
        const int b = hb * 2 + (wv >> 1);
        const int* hidx = (wv & 1) ? hist_cate : hist_item;
        float acc = 0.f;
        for (int t = 0; t < TT; ++t) {
            float m = mask[(size_t)b * TT + t];
            int idx = hidx[(size_t)b * TT + t];
            acc += m * emb[(size_t)idx * 64 + lane];
        }
        hist_sum[(size_t)b * 128 + (wv & 1) * 64 + lane] = acc;
        if ((wv & 1) == 0) {
            float s = 0.f;
            for (int t = lane; t < TT; t += 64) s += mask[(size_t)b * TT + t];
            s = wsum64(s);
            if (lane == 0) seqlen[b] = (int)(s + 0.5f);
        }
    }
}

// ---------------- K2: recurrence, 512 thr (8 waves), RPB=4, MFMA ---------------
// Co-residency experiment: RPB 8->4, grid 512 (2 blocks/CU target). Hypothesis:
// round 6's 2-serial-pass failure was the CONCURRENT-workgroup LDS budget
// (64 KB): 2x37.9 KB > 64 KB blocked the 2nd block. Now LDS ~19.4 KB/block
// -> 38.8 KB for two. Two independent barrier groups per CU fill the ~33%
// barrier/latency stall (VALUBusy 67%) of the lockstep 4-barrier loop.
// Roles (wave-uniform; nlo=lane&15, kg=lane>>4):
//   all waves:  rz gate N-tile wv (rows 16wv..16wv+15 of [0,128)), WG[6];
//               Wp tiles {wv+8i, i<4} (rows 0..511), WP[8]; ph3.
//   waves 0-3:  GRU + NTM for batch row wv (phases 2/4); GI prefetch; M/h regs.
//   waves 4-7:  n-gate N-tile wv-4 (rows 128..191), WN[6], accI/accH split.
//   Wp tail rows 512/513: scalar dot by tid<8 from sWpT.
__global__ __attribute__((amdgpu_flat_work_group_size(512, 512))) void mimn_rnn(
    const int* __restrict__ hist_item, const int* __restrict__ hist_cate,
    const float* __restrict__ mask,
    const float* __restrict__ Wih,   // 192x256 (cols 128..255 = read part)
    const float* __restrict__ Whh,   // 192x64
    const float* __restrict__ bhh,   // 192
    const float* __restrict__ Wp,    // 514x64
    const float* __restrict__ bp,    // 514
    const float* __restrict__ Wo,    // 64x192
    const float* __restrict__ bo,    // 64
    const float* __restrict__ M0,    // 4x128
    const float* __restrict__ GIi, const float* __restrict__ GIc,
    const int* __restrict__ seqlen,
    float* __restrict__ last_out)    // B x 64
{
    // sU time-multiplexed (f32), RPB=4:
    //  ph1/2: rzU [m][n<128] stride 132 @0 (528) | inU [m][n64] stride 68
    //         @528 (272) | hnU stride 68 @800 (272)
    //  ph3/4: pU [m][n<514] stride 520 @0 (2080); cols 0..191 reused as the
    //         rn-stash in the t==ts epilogue (after all PV reads)
    __shared__ __align__(16) float sU[2080];
    __shared__ __align__(16) _Float16 act16[16 * 200]; // [0,128)=read,[128,192)=h
    __shared__ __align__(16) _Float16 hn16[16 * 72];   // unmasked h_new (f16)
    __shared__ float sHnF[RPB * 64];                   // unmasked h_new (f32)
    __shared__ float sWpT[2 * 64];                     // Wp rows 512,513 (f32)
    __shared__ unsigned char sMaskB[RPB * TT];

    const int tid = threadIdx.x;
    const int b0 = blockIdx.x * RPB;
    const int wv = tid >> 6, lane = tid & 63;
    const int nlo = lane & 15, kg = lane >> 4;   // MFMA: n-low, row-group
    const bool isNTM = wv < 4;                   // waves 0-3 own batch rows
    const bool hasN = wv >= 4;                   // waves 4-7 carry the n-gate tile

    // ---- init staged state ----
    for (int i = tid; i < 16 * 200; i += 512) act16[i] = (_Float16)0.f;
    for (int i = tid; i < 16 * 72; i += 512) hn16[i] = (_Float16)0.f;
    for (int i = tid; i < RPB * 64; i += 512) sHnF[i] = 0.f;
    if (tid < 128) sWpT[tid] = Wp[512 * 64 + tid];
    for (int i = tid; i < RPB * TT; i += 512) {
        int r = i / TT, tt = i - r * TT;
        sMaskB[i] = (mask[(size_t)(b0 + r) * TT + tt] > 0.f) ? 1 : 0;
    }

    // ---- wave-private register state (rows owned by waves 0-3) ----
    float hreg = 0.f;                 // committed h, element `lane` of row wv
    float M1[4], M2[4];               // memory row wv, slots s, elems lane/64+lane
#pragma unroll
    for (int s = 0; s < 4; ++s) {
        M1[s] = M0[s * 128 + lane];
        M2[s] = M0[s * 128 + 64 + lane];
    }
    // bias scalars (folded into partial stores)
    const float bhhRZ = bhh[16 * wv + nlo];
    const float bhhN  = hasN ? bhh[128 + 16 * (wv - 4) + nlo] : 0.f;
    float bpP[4];
#pragma unroll
    for (int i = 0; i < 4; ++i) bpP[i] = bp[16 * (wv + 8 * i) + nlo];
    const float bpT = (tid < 8) ? bp[512 + (tid >> 2)] : 0.f;

    // ---- weight fragments (one-time global loads) ----
    // B-frag layout 16x16x32_f16: lane holds W[n=16*tile+nlo][k=32*kb+8*kg+j]
    half8 WG[6];
    {
        int n = 16 * wv + nlo;          // r,z rows: n in [0,128), K=192 combined
#pragma unroll
        for (int kb = 0; kb < 6; ++kb) {
            half8 f;
#pragma unroll
            for (int j = 0; j < 8; ++j) {
                int k = 32 * kb + 8 * kg + j;
                float w = (k < 128) ? Wih[n * 256 + 128 + k] : Whh[n * 64 + (k - 128)];
                f[j] = (_Float16)w;
            }
            WG[kb] = f;
        }
    }
    half8 WN[6];
    if (hasN) {                         // n-gate rows: n in [128,192)
        int n = 128 + 16 * (wv - 4) + nlo;
#pragma unroll
        for (int kb = 0; kb < 4; ++kb) {   // i_n: act cols 0..127 (read)
            half8 f;
#pragma unroll
            for (int j = 0; j < 8; ++j) f[j] = (_Float16)Wih[n * 256 + 128 + 32 * kb + 8 * kg + j];
            WN[kb] = f;
        }
#pragma unroll
        for (int kb = 0; kb < 2; ++kb) {   // h_n: h cols 0..63
            half8 f;
#pragma unroll
            for (int j = 0; j < 8; ++j) f[j] = (_Float16)Whh[n * 64 + 32 * kb + 8 * kg + j];
            WN[4 + kb] = f;
        }
    } else {
#pragma unroll
        for (int q = 0; q < 6; ++q) WN[q] = half8{};
    }
    // Wp fragments: tiles wv+8i (i<4) -> 32 tiles = rows 0..511
    half8 WP[8];
#pragma unroll
    for (int i = 0; i < 4; ++i) {
        int n = 16 * (wv + 8 * i) + nlo;
#pragma unroll
        for (int kb = 0; kb < 2; ++kb) {
            half8 f;
#pragma unroll
            for (int j = 0; j < 8; ++j) f[j] = (_Float16)Wp[n * 64 + 32 * kb + 8 * kg + j];
            WP[2 * i + kb] = f;
        }
    }

    int ts = seqlen[b0 + (wv & 3)] - 1;
    ts = ts < 0 ? 0 : (ts > TT - 1 ? TT - 1 : ts);

    // ---- initial GI load (t = 0): one element per lane, ph2 layout ----
    float giA = 0.f, giB = 0.f, giC = 0.f, gcA = 0.f, gcB = 0.f, gcC = 0.f;
    if (isNTM) {
        int ri = hist_item[(size_t)(b0 + wv) * TT];
        int rc = hist_cate[(size_t)(b0 + wv) * TT];
        giA = GIi[(size_t)ri * GG + lane];
        giB = GIi[(size_t)ri * GG + 64 + lane];
        giC = GIi[(size_t)ri * GG + 128 + lane];
        gcA = GIc[(size_t)rc * GG + lane];
        gcB = GIc[(size_t)rc * GG + 64 + lane];
        gcC = GIc[(size_t)rc * GG + 128 + lane];
    }
    __syncthreads();   // init visible (full drain OK once)

    for (int t = 0; t < TT; ++t) {
        // ---- phase 1: gate GEMMs (A rows = batch from act16; rows 4-15 zero) ----
        {
            const int abase = nlo * 200 + 8 * kg;
            floatx4 accRZ = {0.f, 0.f, 0.f, 0.f};
            floatx4 accI = {0.f, 0.f, 0.f, 0.f};
            floatx4 accH = {0.f, 0.f, 0.f, 0.f};
            half8 a0 = *(const half8*)&act16[abase];
            half8 a1 = *(const half8*)&act16[abase + 32];
            half8 a2 = *(const half8*)&act16[abase + 64];
            accRZ = MFMA16(a0, WG[0], accRZ);
            accRZ = MFMA16(a1, WG[1], accRZ);
            accRZ = MFMA16(a2, WG[2], accRZ);
            if (hasN) {
                accI = MFMA16(a0, WN[0], accI);
                accI = MFMA16(a1, WN[1], accI);
                accI = MFMA16(a2, WN[2], accI);
            }
            a0 = *(const half8*)&act16[abase + 96];
            a1 = *(const half8*)&act16[abase + 128];
            a2 = *(const half8*)&act16[abase + 160];
            accRZ = MFMA16(a0, WG[3], accRZ);
            accRZ = MFMA16(a1, WG[4], accRZ);
            accRZ = MFMA16(a2, WG[5], accRZ);
            if (hasN) {
                accI = MFMA16(a0, WN[3], accI);
                accH = MFMA16(a1, WN[4], accH);
                accH = MFMA16(a2, WN[5], accH);
            }
            if (kg == 0) {               // batch rows 0-3 real (m = q)
                int n = 16 * wv + nlo;
#pragma unroll
                for (int q = 0; q < 4; ++q) sU[q * 132 + n] = accRZ[q] + bhhRZ;
                if (hasN) {
                    int n64 = 16 * (wv - 4) + nlo;
#pragma unroll
                    for (int q = 0; q < 4; ++q) {
                        sU[528 + q * 68 + n64] = accI[q];
                        sU[800 + q * 68 + n64] = accH[q] + bhhN;
                    }
                }
            }
        }
        BARRIER_LDS();                                     // B1
        // ---- phase 2: GRU gates; commit h (waves 0-3, row = wave) ----
        bool vld = false;
        if (isNTM) {
            const int r = wv;
            float g_r = sU[r * 132 + lane] + giA + gcA;          // bhh folded
            float g_z = sU[r * 132 + 64 + lane] + giB + gcB;
            float i_n = sU[528 + r * 68 + lane] + giC + gcC;
            float h_n = sU[800 + r * 68 + lane];                 // bhh folded
            float rg = fsigm(g_r);
            float zg = fsigm(g_z);
            float ng = ftanh(i_n + rg * h_n);
            float hn = (1.f - zg) * ng + zg * hreg;
            vld = sMaskB[r * TT + t] != 0;
            float hc = vld ? hn : hreg;
            hreg = hc;
            act16[r * 200 + 128 + lane] = (_Float16)hc;
            hn16[r * 72 + lane] = (_Float16)hn;
            sHnF[r * 64 + lane] = hn;
            // GI prefetch for t+1 (regs consumed above; in flight one step)
            int tn = (t + 1 < TT) ? t + 1 : TT - 1;
            int ri = hist_item[(size_t)(b0 + wv) * TT + tn];
            int rc = hist_cate[(size_t)(b0 + wv) * TT + tn];
            giA = GIi[(size_t)ri * GG + lane];
            giB = GIi[(size_t)ri * GG + 64 + lane];
            giC = GIi[(size_t)ri * GG + 128 + lane];
            gcA = GIc[(size_t)rc * GG + lane];
            gcB = GIc[(size_t)rc * GG + 64 + lane];
            gcC = GIc[(size_t)rc * GG + 128 + lane];
        }
        BARRIER_LDS();                                     // B2
        // ---- phase 3: p = hn @ Wp^T (8 waves x 4 tiles, bias folded) + tail ----
        {
            const int bbase = nlo * 72 + 8 * kg;
            half8 b0f = *(const half8*)&hn16[bbase];
            half8 b1f = *(const half8*)&hn16[bbase + 32];
#pragma unroll
            for (int i = 0; i < 4; ++i) {
                floatx4 acc = {0.f, 0.f, 0.f, 0.f};
                acc = MFMA16(b0f, WP[2 * i], acc);
                acc = MFMA16(b1f, WP[2 * i + 1], acc);
                if (kg == 0) {
                    int n = 16 * (wv + 8 * i) + nlo;
#pragma unroll
                    for (int q = 0; q < 4; ++q) sU[q * 520 + n] = acc[q] + bpP[i];
                }
            }
        }
        if (tid < 8) {                   // Wp tail rows 512,513 (scalar, f32)
            int r = tid & 3, j = tid >> 2;
            float acc = 0.f;
#pragma unroll
            for (int k = 0; k < 64; ++k) acc += sHnF[r * 64 + k] * sWpT[j * 64 + k];
            sU[r * 520 + 512 + j] = acc + bpT;
        }
        BARRIER_LDS();                                     // B3
        // ---- phase 4: NTM addressing (waves 0-3, row = wave; M in regs) ----
        if (isNTM) {
            const int row = wv;
            const int pb = row * 520;
#define PV(n) (sU[pb + (n)])
            float kr1 = ftanh(PV(lane)),       kr2 = ftanh(PV(64 + lane));
            float beta_r = fsoftplus(PV(128));
            float kw1 = ftanh(PV(129 + lane)), kw2 = ftanh(PV(193 + lane));
            float beta_w = fsoftplus(PV(257));
            float er1 = fsigm(PV(258 + lane)), er2 = fsigm(PV(322 + lane));
            float ad1 = ftanh(PV(386 + lane)), ad2 = ftanh(PV(450 + lane));
#undef PV
            float nkr = sqrtf(wsum64(kr1 * kr1 + kr2 * kr2)) + 1e-8f;
            float nkw = sqrtf(wsum64(kw1 * kw1 + kw2 * kw2)) + 1e-8f;
            float Kr[4], Kw[4];
#pragma unroll
            for (int s = 0; s < 4; ++s) {
                float nM = sqrtf(wsum64(M1[s] * M1[s] + M2[s] * M2[s])) + 1e-8f;
                float dr = wsum64(kr1 * M1[s] + kr2 * M2[s]);
                float dw = wsum64(kw1 * M1[s] + kw2 * M2[s]);
                Kr[s] = dr / (nkr * nM);
                Kw[s] = dw / (nkw * nM);
            }
            float wr_[4], ww_[4];
            {
                float mx = fmaxf(fmaxf(beta_r * Kr[0], beta_r * Kr[1]),
                                 fmaxf(beta_r * Kr[2], beta_r * Kr[3]));
                float sum = 0.f;
#pragma unroll
                for (int s = 0; s < 4; ++s) { wr_[s] = __expf(beta_r * Kr[s] - mx); sum += wr_[s]; }
                float inv = 1.f / sum;
#pragma unroll
                for (int s = 0; s < 4; ++s) wr_[s] *= inv;
            }
            {
                float mx = fmaxf(fmaxf(beta_w * Kw[0], beta_w * Kw[1]),
                                 fmaxf(beta_w * Kw[2], beta_w * Kw[3]));
                float sum = 0.f;
#pragma unroll
                for (int s = 0; s < 4; ++s) { ww_[s] = __expf(beta_w * Kw[s] - mx); sum += ww_[s]; }
                float inv = 1.f / sum;
#pragma unroll
                for (int s = 0; s < 4; ++s) ww_[s] *= inv;
            }
            float rn1 = 0.f, rn2 = 0.f;
#pragma unroll
            for (int s = 0; s < 4; ++s) { rn1 += wr_[s] * M1[s]; rn2 += wr_[s] * M2[s]; }
            if (vld) {                   // wave-uniform branch
#pragma unroll
                for (int s = 0; s < 4; ++s) {
                    M1[s] = M1[s] * (1.f - ww_[s] * er1) + ww_[s] * ad1;
                    M2[s] = M2[s] * (1.f - ww_[s] * er2) + ww_[s] * ad2;
                }
                act16[row * 200 + lane]      = (_Float16)rn1;   // committed read
                act16[row * 200 + 64 + lane] = (_Float16)rn2;
            }
            if (t == ts) {
                // out = [h_new, read_new] @ Wo^T + bo  (unmasked values)
                // stash rn into this row's pU cols 0..191 (all PV reads done)
                float* stash = &sU[pb];
                stash[lane] = rn1; stash[64 + lane] = rn2;
                __asm__ volatile("s_waitcnt lgkmcnt(0)" ::: "memory");
                float acc = bo[lane];
                const float* wo = Wo + lane * GG;
                for (int k = 0; k < 64; ++k)  acc += sHnF[row * 64 + k] * wo[k];
                for (int k = 0; k < 128; ++k) acc += stash[k] * wo[64 + k];
                if (!vld) acc = 0.f;
                last_out[(size_t)(b0 + row) * 64 + lane] = acc;
            }
        }
        BARRIER_LDS();                                     // B4
    }
}

// ---------------- K3: final MLP head --------------------------------------------
__global__ __launch_bounds__(128) void final_mlp(
    const int* __restrict__ item, const int* __restrict__ cate,
    const float* __restrict__ emb,
    const float* __restrict__ hist_sum, const float* __restrict__ last_out,
    const float* __restrict__ fc1w, const float* __restrict__ fc1b,
    const float* __restrict__ pa1,
    const float* __restrict__ fc2w, const float* __restrict__ fc2b,
    const float* __restrict__ pa2,
    const float* __restrict__ fc3w, const float* __restrict__ fc3b,
    float* __restrict__ out)
{
    __shared__ float sX[320], sH1[200], sH2[80];
    int b = blockIdx.x, tid = threadIdx.x;
    int it = item[b], ct = cate[b];
    for (int i = tid; i < 320; i += 128) {
        float val;
        if (i < 64)       val = emb[(size_t)it * 64 + i];
        else if (i < 128) val = emb[(size_t)ct * 64 + (i - 64)];
        else if (i < 256) val = hist_sum[(size_t)b * 128 + (i - 128)];
        else              val = last_out[(size_t)b * 64 + (i - 256)];
        sX[i] = val;
    }
    __syncthreads();
    float a1 = pa1[0];
    for (int o = tid; o < 200; o += 128) {
        const float4* w = (const float4*)(fc1w + o * 320);
        float acc = fc1b[o];
#pragma unroll
        for (int q = 0; q < 80; ++q) acc += dot4(w[q], *(const float4*)&sX[q * 4]);
        sH1[o] = acc > 0.f ? acc : a1 * acc;
    }
    __syncthreads();
    float a2 = pa2[0];
    for (int o = tid; o < 80; o += 128) {
        const float4* w = (const float4*)(fc2w + o * 200);
        float acc = fc2b[o];
#pragma unroll
        for (int q = 0; q < 50; ++q) acc += dot4(w[q], *(const float4*)&sH1[q * 4]);
        sH2[o] = acc > 0.f ? acc : a2 * acc;
    }
    __syncthreads();
    if (tid < 2) {
        const float4* w = (const float4*)(fc3w + tid * 80);
        float acc = fc3b[tid];
#pragma unroll
        for (int q = 0; q < 20; ++q) acc += dot4(w[q], *(const float4*)&sH2[q * 4]);
        out[b * 2 + tid] = acc;
    }
}

extern "C" void kernel_launch(void* const* d_in, const int* in_sizes, int n_in,
                              void* d_out, int out_size, void* d_ws, size_t ws_size,
                              hipStream_t stream) {
    (void)in_sizes; (void)n_in; (void)out_size; (void)ws_size;
    const int*   item      = (const int*)d_in[0];
    const int*   cate      = (const int*)d_in[1];
    const int*   hist_item = (const int*)d_in[2];
    const int*   hist_cate = (const int*)d_in[3];
    const float* mask = (const float*)d_in[4];
    const float* emb  = (const float*)d_in[5];
    const float* Wih  = (const float*)d_in[6];
    const float* Whh  = (const float*)d_in[7];
    const float* bih  = (const float*)d_in[8];
    const float* bhh  = (const float*)d_in[9];
    const float* Wp   = (const float*)d_in[10];
    const float* bp   = (const float*)d_in[11];
    const float* Wo   = (const float*)d_in[12];
    const float* bo   = (const float*)d_in[13];
    const float* M0   = (const float*)d_in[14];
    const float* fc1w = (const float*)d_in[15];
    const float* fc1b = (const float*)d_in[16];
    const float* pa1  = (const float*)d_in[17];
    const float* fc2w = (const float*)d_in[18];
    const float* fc2b = (const float*)d_in[19];
    const float* pa2  = (const float*)d_in[20];
    const float* fc3w = (const float*)d_in[21];
    const float* fc3b = (const float*)d_in[22];

    float* GIi = (float*)d_ws;                                   // V*192 f32
    float* GIc = GIi + (size_t)VV * GG;                          // V*192 f32
    float* hist_sum = GIc + (size_t)VV * GG;                     // B*128 f32
    float* last_out = hist_sum + (size_t)BB * 128;               // B*64 f32
    int* seqlen = (int*)(last_out + (size_t)BB * 64);            // B int

    prep<<<NBT + BB / 2, 256, 0, stream>>>(emb, Wih, bih, hist_item, hist_cate,
                                           mask, GIi, GIc, hist_sum, seqlen);
    mimn_rnn<<<BB / RPB, 512, 0, stream>>>(hist_item, hist_cate, mask, Wih, Whh, bhh,
                                           Wp, bp, Wo, bo, M0, GIi, GIc, seqlen, last_out);
    final_mlp<<<BB, 128, 0, stream>>>(item, cate, emb, hist_sum, last_out,
                                      fc1w, fc1b, pa1, fc2w, fc2b, pa2, fc3w, fc3b,
                                      (float*)d_out);
}

// Round 13
// 1060.374 us; speedup vs baseline: 1.3967x; 1.3967x over previous
//
#include <hip/hip_runtime.h>

#define VV 100000
#define BB 2048
#define TT 200
#define GG 192   // 3*C
#define PP 514
#define RPB 8    // batch rows per block (mimn_rnn)
#define NBT 1563 // ceil(VV/64) build-table blocks in prep

typedef _Float16 half8 __attribute__((ext_vector_type(8)));
typedef float floatx4 __attribute__((ext_vector_type(4)));
#define MFMA16(a, b, c) __builtin_amdgcn_mfma_f32_16x16x32_f16((a), (b), (c), 0, 0, 0)

// LDS-only barrier: all 4 phase barriers only publish LDS data ->
// lgkmcnt(0) suffices (no vmcnt drain of in-flight GI prefetch loads).
#define BARRIER_LDS() do { \
    __asm__ volatile("s_waitcnt lgkmcnt(0)" ::: "memory"); \
    __builtin_amdgcn_s_barrier(); } while (0)

__device__ __forceinline__ float fsigm(float x) { return 1.0f / (1.0f + __expf(-x)); }
__device__ __forceinline__ float ftanh(float x) {
    // 1 - 2/(e^{2x}+1): saturates correctly for |x| large (inf-safe)
    float e = __expf(2.0f * x);
    return 1.0f - 2.0f / (e + 1.0f);
}
__device__ __forceinline__ float fsoftplus(float x) {
    float e = __expf(-fabsf(x));
    return fmaxf(x, 0.0f) + __logf(1.0f + e);
}

// DPP wave64 sum: 6 v_add_f32_dpp + readlane, no LDS.
#define DPP_ADD(x, ctrl, rmask) \
    ((x) + __int_as_float(__builtin_amdgcn_update_dpp( \
        0, __float_as_int(x), (ctrl), (rmask), 0xf, true)))
__device__ __forceinline__ float wsum64(float x) {
    x = DPP_ADD(x, 0x111, 0xf);   // row_shr:1
    x = DPP_ADD(x, 0x112, 0xf);   // row_shr:2
    x = DPP_ADD(x, 0x114, 0xf);   // row_shr:4
    x = DPP_ADD(x, 0x118, 0xf);   // row_shr:8
    x = DPP_ADD(x, 0x142, 0xa);   // row_bcast:15 -> rows 1,3
    x = DPP_ADD(x, 0x143, 0xc);   // row_bcast:31 -> rows 2,3
    return __int_as_float(__builtin_amdgcn_readlane(__float_as_int(x), 63));
}
__device__ __forceinline__ float dot4(float4 w, float4 a) {
    return w.x * a.x + w.y * a.y + w.z * a.z + w.w * a.w;
}

// ---------------- K0: fused prep — MFMA table build + hist stats ----------------
// blocks [0, NBT): GI tables via f16 MFMA (f32 accum), 64 vocab rows/block.
// blocks [NBT, NBT+BB/2): hist_sum + seqlen, 2 batch rows per 256-thr block.
__global__ __launch_bounds__(256) void prep(
    const float* __restrict__ emb,   // V x 64
    const float* __restrict__ Wih,   // 192 x 256
    const float* __restrict__ bih,   // 192
    const int* __restrict__ hist_item, const int* __restrict__ hist_cate,
    const float* __restrict__ mask,
    float* __restrict__ GIi, float* __restrict__ GIc,  // V x 192 each
    float* __restrict__ hist_sum, int* __restrict__ seqlen)
{
    __shared__ __align__(16) _Float16 sE16[64 * 72];   // emb tile, padded rows
    const int tid = threadIdx.x;
    const int wv = tid >> 6, lane = tid & 63;
    const int nlo = lane & 15, kg = lane >> 4;

    if (blockIdx.x < NBT) {
        const int v0 = blockIdx.x * 64;
        // stage emb rows v0..v0+63 as f16 (zero-pad OOB vocab)
        for (int i = tid; i < 64 * 64; i += 256) {
            int vv = i >> 6, k = i & 63;
            int gv = v0 + vv;
            sE16[vv * 72 + k] = (gv < VV) ? (_Float16)emb[(size_t)gv * 64 + k]
                                          : (_Float16)0.f;
        }
        // weight fragments: wave wv owns pairs pid = 6*wv + j over
        // 24 = {item(12 n-tiles), cate(12 n-tiles)}; K=64 -> 2 half8 each
        half8 WF[6][2];
        float bias[6];
#pragma unroll
        for (int j = 0; j < 6; ++j) {
            int pid = 6 * wv + j;
            int tb = pid / 12, nt = pid % 12;
            int n = nt * 16 + nlo;
#pragma unroll
            for (int kb = 0; kb < 2; ++kb) {
                half8 f;
#pragma unroll
                for (int q = 0; q < 8; ++q)
                    f[q] = (_Float16)Wih[n * 256 + tb * 64 + kb * 32 + kg * 8 + q];
                WF[j][kb] = f;
            }
            bias[j] = tb ? 0.f : bih[n];
        }
        __syncthreads();
#pragma unroll
        for (int mt = 0; mt < 4; ++mt) {
            const int ar = (16 * mt + nlo) * 72 + 8 * kg;
            half8 a0 = *(const half8*)&sE16[ar];
            half8 a1 = *(const half8*)&sE16[ar + 32];
#pragma unroll
            for (int j = 0; j < 6; ++j) {
                floatx4 acc = {0.f, 0.f, 0.f, 0.f};
                acc = MFMA16(a0, WF[j][0], acc);
                acc = MFMA16(a1, WF[j][1], acc);
                int pid = 6 * wv + j;
                int tb = pid / 12, nt = pid % 12;
                float* dst = tb ? GIc : GIi;
                int n = nt * 16 + nlo;
#pragma unroll
                for (int q = 0; q < 4; ++q) {
                    int gv = v0 + 16 * mt + 4 * kg + q;
                    if (gv < VV) dst[(size_t)gv * GG + n] = acc[q] + bias[j];
                }
            }
        }
    } else {
        // hist path: 2 batch rows/block; waves {0,1}=row A (item/cate),
        // waves {2,3}=row B
        const int hb = blockIdx.x - NBT;
        const int b = hb * 2 + (wv >> 1);
        const int* hidx = (wv & 1) ? hist_cate : hist_item;
        float acc = 0.f;
        for (int t = 0; t < TT; ++t) {
            float m = mask[(size_t)b * TT + t];
            int idx = hidx[(size_t)b * TT + t];
            acc += m * emb[(size_t)idx * 64 + lane];
        }
        hist_sum[(size_t)b * 128 + (wv & 1) * 64 + lane] = acc;
        if ((wv & 1) == 0) {
            float s = 0.f;
            for (int t = lane; t < TT; t += 64) s += mask[(size_t)b * TT + t];
            s = wsum64(s);
            if (lane == 0) seqlen[b] = (int)(s + 0.5f);
        }
    }
}

// ---------------- K2: recurrence, 512 thr (8 waves), RPB=8, MFMA ---------------
// Round-11 verified best (869 us) + deferred NTM write-path:
// ph4's write path (kw/beta_w/erase/add -> w_w -> M update) touches only
// wave-private register state (M1/M2); nothing reads it until the NEXT step's
// ph4. So ph4 saves the 7 raw write-path PV values + 4 nM norms to regs and
// commits only the read path before B4; the write path (5 wsum64 + 7
// transcendentals + M update) runs at the top of the next iteration,
// overlapping ph1's MFMA issue and the B1 stall. Reference ordering preserved:
// both w_r and w_w of step t use pre-update M; update applies before ph4(t+1).
// Co-residency (2 blocks/CU) empirically impossible (R6: 37.9KB, R12: 19.4KB
// both ran 2 serial passes) — grid 256 = 1 block/CU is the design point.
__global__ __attribute__((amdgpu_flat_work_group_size(512, 512))) void mimn_rnn(
    const int* __restrict__ hist_item, const int* __restrict__ hist_cate,
    const float* __restrict__ mask,
    const float* __restrict__ Wih,   // 192x256 (cols 128..255 = read part)
    const float* __restrict__ Whh,   // 192x64
    const float* __restrict__ bhh,   // 192
    const float* __restrict__ Wp,    // 514x64
    const float* __restrict__ bp,    // 514
    const float* __restrict__ Wo,    // 64x192
    const float* __restrict__ bo,    // 64
    const float* __restrict__ M0,    // 4x128
    const float* __restrict__ GIi, const float* __restrict__ GIc,
    const int* __restrict__ seqlen,
    float* __restrict__ last_out)    // B x 64
{
    // sU time-multiplexed (f32):
    //  ph1/2: rzU [m][n<128] stride 132 @0 (1056) | inU [m][n64] stride 68
    //         @1056 (544) | hnU stride 68 @1600 (544)
    //  ph3/4: pU [m][n<514] stride 520 @0 (4160); cols 0..191 reused as the
    //         rn-stash in the t==ts epilogue (after all PV reads)
    __shared__ __align__(16) float sU[4160];
    __shared__ __align__(16) _Float16 act16[16 * 200]; // [0,128)=read,[128,192)=h
    __shared__ __align__(16) _Float16 hn16[16 * 72];   // unmasked h_new (f16)
    __shared__ float sHnF[RPB * 64];                   // unmasked h_new (f32)
    __shared__ float sWpT[2 * 64];                     // Wp rows 512,513 (f32)
    __shared__ unsigned char sMaskB[RPB * TT];

    const int tid = threadIdx.x;
    const int b0 = blockIdx.x * RPB;
    const int wv = tid >> 6, lane = tid & 63;
    const int nlo = lane & 15, kg = lane >> 4;   // MFMA: n-low, row-group
    const bool hasN = wv >= 4;                   // waves 4-7 carry the n-gate tile

    // ---- init staged state ----
    for (int i = tid; i < 16 * 200; i += 512) act16[i] = (_Float16)0.f;
    for (int i = tid; i < 16 * 72; i += 512) hn16[i] = (_Float16)0.f;
    for (int i = tid; i < RPB * 64; i += 512) sHnF[i] = 0.f;
    if (tid < 128) sWpT[tid] = Wp[512 * 64 + tid];
    for (int i = tid; i < RPB * TT; i += 512) {
        int r = i / TT, tt = i - r * TT;
        sMaskB[i] = (mask[(size_t)(b0 + r) * TT + tt] > 0.f) ? 1 : 0;
    }

    // ---- wave-private register state ----
    float hreg = 0.f;                 // committed h, element `lane` of row wv
    float M1[4], M2[4];               // memory row wv, slots s, elems lane/64+lane
#pragma unroll
    for (int s = 0; s < 4; ++s) {
        M1[s] = M0[s * 128 + lane];
        M2[s] = M0[s * 128 + 64 + lane];
    }
    // bias scalars (folded into partial stores)
    const float bhhRZ = bhh[16 * wv + nlo];
    const float bhhN  = hasN ? bhh[128 + 16 * (wv - 4) + nlo] : 0.f;
    float bpP[4];
#pragma unroll
    for (int i = 0; i < 4; ++i) bpP[i] = bp[16 * (wv + 8 * i) + nlo];
    const float bpT = (tid < 16) ? bp[512 + (tid >> 3)] : 0.f;

    // ---- weight fragments (one-time global loads) ----
    // B-frag layout 16x16x32_f16: lane holds W[n=16*tile+nlo][k=32*kb+8*kg+j]
    half8 WG[6];
    {
        int n = 16 * wv + nlo;          // r,z rows: n in [0,128), K=192 combined
#pragma unroll
        for (int kb = 0; kb < 6; ++kb) {
            half8 f;
#pragma unroll
            for (int j = 0; j < 8; ++j) {
                int k = 32 * kb + 8 * kg + j;
                float w = (k < 128) ? Wih[n * 256 + 128 + k] : Whh[n * 64 + (k - 128)];
                f[j] = (_Float16)w;
            }
            WG[kb] = f;
        }
    }
    half8 WN[6];
    if (hasN) {                         // n-gate rows: n in [128,192)
        int n = 128 + 16 * (wv - 4) + nlo;
#pragma unroll
        for (int kb = 0; kb < 4; ++kb) {   // i_n: act cols 0..127 (read)
            half8 f;
#pragma unroll
            for (int j = 0; j < 8; ++j) f[j] = (_Float16)Wih[n * 256 + 128 + 32 * kb + 8 * kg + j];
            WN[kb] = f;
        }
#pragma unroll
        for (int kb = 0; kb < 2; ++kb) {   // h_n: h cols 0..63
            half8 f;
#pragma unroll
            for (int j = 0; j < 8; ++j) f[j] = (_Float16)Whh[n * 64 + 32 * kb + 8 * kg + j];
            WN[4 + kb] = f;
        }
    } else {
#pragma unroll
        for (int q = 0; q < 6; ++q) WN[q] = half8{};
    }
    // Wp fragments: tiles wv+8i (i<4) -> 32 tiles = rows 0..511
    half8 WP[8];
#pragma unroll
    for (int i = 0; i < 4; ++i) {
        int n = 16 * (wv + 8 * i) + nlo;
#pragma unroll
        for (int kb = 0; kb < 2; ++kb) {
            half8 f;
#pragma unroll
            for (int j = 0; j < 8; ++j) f[j] = (_Float16)Wp[n * 64 + 32 * kb + 8 * kg + j];
            WP[2 * i + kb] = f;
        }
    }

    int ts = seqlen[b0 + wv] - 1;
    ts = ts < 0 ? 0 : (ts > TT - 1 ? TT - 1 : ts);

    // ---- initial GI load (t = 0): one element per lane, ph2 layout ----
    float giA, giB, giC, gcA, gcB, gcC;
    {
        int ri = hist_item[(size_t)(b0 + wv) * TT];
        int rc = hist_cate[(size_t)(b0 + wv) * TT];
        giA = GIi[(size_t)ri * GG + lane];
        giB = GIi[(size_t)ri * GG + 64 + lane];
        giC = GIi[(size_t)ri * GG + 128 + lane];
        gcA = GIc[(size_t)rc * GG + lane];
        gcB = GIc[(size_t)rc * GG + 64 + lane];
        gcC = GIc[(size_t)rc * GG + 128 + lane];
    }
    // deferred write-path state (set in ph4, consumed next iteration's ph1)
    float pKw1 = 0.f, pKw2 = 0.f, pBw = 0.f, pEr1 = 0.f, pEr2 = 0.f;
    float pAd1 = 0.f, pAd2 = 0.f;
    float nMs[4] = {1.f, 1.f, 1.f, 1.f};
    bool vldPrev = false;
    __syncthreads();   // init visible (full drain OK once)

    for (int t = 0; t < TT; ++t) {
        // ---- phase 1: gate GEMMs + deferred M update (overlaps MFMA) ----
        {
            const int abase = nlo * 200 + 8 * kg;
            floatx4 accRZ = {0.f, 0.f, 0.f, 0.f};
            floatx4 accI = {0.f, 0.f, 0.f, 0.f};
            floatx4 accH = {0.f, 0.f, 0.f, 0.f};
            half8 a0 = *(const half8*)&act16[abase];
            half8 a1 = *(const half8*)&act16[abase + 32];
            half8 a2 = *(const half8*)&act16[abase + 64];
            accRZ = MFMA16(a0, WG[0], accRZ);
            accRZ = MFMA16(a1, WG[1], accRZ);
            accRZ = MFMA16(a2, WG[2], accRZ);
            if (hasN) {
                accI = MFMA16(a0, WN[0], accI);
                accI = MFMA16(a1, WN[1], accI);
                accI = MFMA16(a2, WN[2], accI);
            }
            a0 = *(const half8*)&act16[abase + 96];
            a1 = *(const half8*)&act16[abase + 128];
            a2 = *(const half8*)&act16[abase + 160];
            accRZ = MFMA16(a0, WG[3], accRZ);
            accRZ = MFMA16(a1, WG[4], accRZ);
            accRZ = MFMA16(a2, WG[5], accRZ);
            if (hasN) {
                accI = MFMA16(a0, WN[3], accI);
                accH = MFMA16(a1, WN[4], accH);
                accH = MFMA16(a2, WN[5], accH);
            }
            // deferred NTM write path of step t-1 (register-only; overlaps
            // the MFMA latency + B1 stall)
            if (t > 0) {
                float kw1 = ftanh(pKw1), kw2 = ftanh(pKw2);
                float beta_w = fsoftplus(pBw);
                float nkw = sqrtf(wsum64(kw1 * kw1 + kw2 * kw2)) + 1e-8f;
                float Kw[4];
#pragma unroll
                for (int s = 0; s < 4; ++s) {
                    float dw = wsum64(kw1 * M1[s] + kw2 * M2[s]);
                    Kw[s] = dw / (nkw * nMs[s]);
                }
                float ww_[4];
                float mx = fmaxf(fmaxf(beta_w * Kw[0], beta_w * Kw[1]),
                                 fmaxf(beta_w * Kw[2], beta_w * Kw[3]));
                float sum = 0.f;
#pragma unroll
                for (int s = 0; s < 4; ++s) { ww_[s] = __expf(beta_w * Kw[s] - mx); sum += ww_[s]; }
                float inv = 1.f / sum;
                if (vldPrev) {
                    float er1 = fsigm(pEr1), er2 = fsigm(pEr2);
                    float ad1 = ftanh(pAd1), ad2 = ftanh(pAd2);
#pragma unroll
                    for (int s = 0; s < 4; ++s) {
                        float w = ww_[s] * inv;
                        M1[s] = M1[s] * (1.f - w * er1) + w * ad1;
                        M2[s] = M2[s] * (1.f - w * er2) + w * ad2;
                    }
                }
            }
            if (kg < 2) {                // batch rows 0-7 real (m = 4*kg+q)
                int n = 16 * wv + nlo;
#pragma unroll
                for (int q = 0; q < 4; ++q) sU[(4 * kg + q) * 132 + n] = accRZ[q] + bhhRZ;
                if (hasN) {
                    int n64 = 16 * (wv - 4) + nlo;
#pragma unroll
                    for (int q = 0; q < 4; ++q) {
                        sU[1056 + (4 * kg + q) * 68 + n64] = accI[q];
                        sU[1600 + (4 * kg + q) * 68 + n64] = accH[q] + bhhN;
                    }
                }
            }
        }
        BARRIER_LDS();                                     // B1
        // ---- phase 2: GRU gates; commit h (all 8 waves, row = wave) ----
        bool vld;
        {
            const int r = wv;
            float g_r = sU[r * 132 + lane] + giA + gcA;          // bhh folded
            float g_z = sU[r * 132 + 64 + lane] + giB + gcB;
            float i_n = sU[1056 + r * 68 + lane] + giC + gcC;
            float h_n = sU[1600 + r * 68 + lane];                // bhh folded
            float rg = fsigm(g_r);
            float zg = fsigm(g_z);
            float ng = ftanh(i_n + rg * h_n);
            float hn = (1.f - zg) * ng + zg * hreg;
            vld = sMaskB[r * TT + t] != 0;
            float hc = vld ? hn : hreg;
            hreg = hc;
            act16[r * 200 + 128 + lane] = (_Float16)hc;
            hn16[r * 72 + lane] = (_Float16)hn;
            sHnF[r * 64 + lane] = hn;
        }
        // ---- GI prefetch for t+1 (regs consumed above; in flight one full step) ----
        {
            int tn = (t + 1 < TT) ? t + 1 : TT - 1;
            int ri = hist_item[(size_t)(b0 + wv) * TT + tn];
            int rc = hist_cate[(size_t)(b0 + wv) * TT + tn];
            giA = GIi[(size_t)ri * GG + lane];
            giB = GIi[(size_t)ri * GG + 64 + lane];
            giC = GIi[(size_t)ri * GG + 128 + lane];
            gcA = GIc[(size_t)rc * GG + lane];
            gcB = GIc[(size_t)rc * GG + 64 + lane];
            gcC = GIc[(size_t)rc * GG + 128 + lane];
        }
        BARRIER_LDS();                                     // B2
        // ---- phase 3: p = hn @ Wp^T (8 waves x 4 tiles, bias folded) + tail ----
        {
            const int bbase = nlo * 72 + 8 * kg;
            half8 b0f = *(const half8*)&hn16[bbase];
            half8 b1f = *(const half8*)&hn16[bbase + 32];
#pragma unroll
            for (int i = 0; i < 4; ++i) {
                floatx4 acc = {0.f, 0.f, 0.f, 0.f};
                acc = MFMA16(b0f, WP[2 * i], acc);
                acc = MFMA16(b1f, WP[2 * i + 1], acc);
                if (kg < 2) {
                    int n = 16 * (wv + 8 * i) + nlo;
#pragma unroll
                    for (int q = 0; q < 4; ++q) sU[(4 * kg + q) * 520 + n] = acc[q] + bpP[i];
                }
            }
        }
        if (tid < 16) {                  // Wp tail rows 512,513 (scalar, f32)
            int r = tid & 7, j = tid >> 3;
            float acc = 0.f;
#pragma unroll
            for (int k = 0; k < 64; ++k) acc += sHnF[r * 64 + k] * sWpT[j * 64 + k];
            sU[r * 520 + 512 + j] = acc + bpT;
        }
        BARRIER_LDS();                                     // B3
        // ---- phase 4: NTM read path; save write-path raws for deferral ----
        {
            const int row = wv;
            const int pb = row * 520;
#define PV(n) (sU[pb + (n)])
            float kr1 = ftanh(PV(lane)),       kr2 = ftanh(PV(64 + lane));
            float beta_r = fsoftplus(PV(128));
            // save raw write-path values (processed next iteration, reg-only)
            pKw1 = PV(129 + lane); pKw2 = PV(193 + lane);
            pBw  = PV(257);
            pEr1 = PV(258 + lane); pEr2 = PV(322 + lane);
            pAd1 = PV(386 + lane); pAd2 = PV(450 + lane);
#undef PV
            float nkr = sqrtf(wsum64(kr1 * kr1 + kr2 * kr2)) + 1e-8f;
            float Kr[4];
#pragma unroll
            for (int s = 0; s < 4; ++s) {
                nMs[s] = sqrtf(wsum64(M1[s] * M1[s] + M2[s] * M2[s])) + 1e-8f;
                float dr = wsum64(kr1 * M1[s] + kr2 * M2[s]);
                Kr[s] = dr / (nkr * nMs[s]);
            }
            float wr_[4];
            {
                float mx = fmaxf(fmaxf(beta_r * Kr[0], beta_r * Kr[1]),
                                 fmaxf(beta_r * Kr[2], beta_r * Kr[3]));
                float sum = 0.f;
#pragma unroll
                for (int s = 0; s < 4; ++s) { wr_[s] = __expf(beta_r * Kr[s] - mx); sum += wr_[s]; }
                float inv = 1.f / sum;
#pragma unroll
                for (int s = 0; s < 4; ++s) wr_[s] *= inv;
            }
            float rn1 = 0.f, rn2 = 0.f;
#pragma unroll
            for (int s = 0; s < 4; ++s) { rn1 += wr_[s] * M1[s]; rn2 += wr_[s] * M2[s]; }
            vldPrev = vld;
            if (vld) {                   // wave-uniform branch
                act16[row * 200 + lane]      = (_Float16)rn1;   // committed read
                act16[row * 200 + 64 + lane] = (_Float16)rn2;
            }
            if (t == ts) {
                // out = [h_new, read_new] @ Wo^T + bo  (unmasked values)
                // stash rn into this row's pU cols 0..191 (all PV reads done)
                float* stash = &sU[pb];
                stash[lane] = rn1; stash[64 + lane] = rn2;
                __asm__ volatile("s_waitcnt lgkmcnt(0)" ::: "memory");
                float acc = bo[lane];
                const float* wo = Wo + lane * GG;
                for (int k = 0; k < 64; ++k)  acc += sHnF[row * 64 + k] * wo[k];
                for (int k = 0; k < 128; ++k) acc += stash[k] * wo[64 + k];
                if (!vld) acc = 0.f;
                last_out[(size_t)(b0 + row) * 64 + lane] = acc;
            }
        }
        BARRIER_LDS();                                     // B4
    }
}

// ---------------- K3: final MLP head --------------------------------------------
__global__ __launch_bounds__(128) void final_mlp(
    const int* __restrict__ item, const int* __restrict__ cate,
    const float* __restrict__ emb,
    const float* __restrict__ hist_sum, const float* __restrict__ last_out,
    const float* __restrict__ fc1w, const float* __restrict__ fc1b,
    const float* __restrict__ pa1,
    const float* __restrict__ fc2w, const float* __restrict__ fc2b,
    const float* __restrict__ pa2,
    const float* __restrict__ fc3w, const float* __restrict__ fc3b,
    float* __restrict__ out)
{
    __shared__ float sX[320], sH1[200], sH2[80];
    int b = blockIdx.x, tid = threadIdx.x;
    int it = item[b], ct = cate[b];
    for (int i = tid; i < 320; i += 128) {
        float val;
        if (i < 64)       val = emb[(size_t)it * 64 + i];
        else if (i < 128) val = emb[(size_t)ct * 64 + (i - 64)];
        else if (i < 256) val = hist_sum[(size_t)b * 128 + (i - 128)];
        else              val = last_out[(size_t)b * 64 + (i - 256)];
        sX[i] = val;
    }
    __syncthreads();
    float a1 = pa1[0];
    for (int o = tid; o < 200; o += 128) {
        const float4* w = (const float4*)(fc1w + o * 320);
        float acc = fc1b[o];
#pragma unroll
        for (int q = 0; q < 80; ++q) acc += dot4(w[q], *(const float4*)&sX[q * 4]);
        sH1[o] = acc > 0.f ? acc : a1 * acc;
    }
    __syncthreads();
    float a2 = pa2[0];
    for (int o = tid; o < 80; o += 128) {
        const float4* w = (const float4*)(fc2w + o * 200);
        float acc = fc2b[o];
#pragma unroll
        for (int q = 0; q < 50; ++q) acc += dot4(w[q], *(const float4*)&sH1[q * 4]);
        sH2[o] = acc > 0.f ? acc : a2 * acc;
    }
    __syncthreads();
    if (tid < 2) {
        const float4* w = (const float4*)(fc3w + tid * 80);
        float acc = fc3b[tid];
#pragma unroll
        for (int q = 0; q < 20; ++q) acc += dot4(w[q], *(const float4*)&sH2[q * 4]);
        out[b * 2 + tid] = acc;
    }
}

extern "C" void kernel_launch(void* const* d_in, const int* in_sizes, int n_in,
                              void* d_out, int out_size, void* d_ws, size_t ws_size,
                              hipStream_t stream) {
    (void)in_sizes; (void)n_in; (void)out_size; (void)ws_size;
    const int*   item      = (const int*)d_in[0];
    const int*   cate      = (const int*)d_in[1];
    const int*   hist_item = (const int*)d_in[2];
    const int*   hist_cate = (const int*)d_in[3];
    const float* mask = (const float*)d_in[4];
    const float* emb  = (const float*)d_in[5];
    const float* Wih  = (const float*)d_in[6];
    const float* Whh  = (const float*)d_in[7];
    const float* bih  = (const float*)d_in[8];
    const float* bhh  = (const float*)d_in[9];
    const float* Wp   = (const float*)d_in[10];
    const float* bp   = (const float*)d_in[11];
    const float* Wo   = (const float*)d_in[12];
    const float* bo   = (const float*)d_in[13];
    const float* M0   = (const float*)d_in[14];
    const float* fc1w = (const float*)d_in[15];
    const float* fc1b = (const float*)d_in[16];
    const float* pa1  = (const float*)d_in[17];
    const float* fc2w = (const float*)d_in[18];
    const float* fc2b = (const float*)d_in[19];
    const float* pa2  = (const float*)d_in[20];
    const float* fc3w = (const float*)d_in[21];
    const float* fc3b = (const float*)d_in[22];

    float* GIi = (float*)d_ws;                                   // V*192 f32
    float* GIc = GIi + (size_t)VV * GG;                          // V*192 f32
    float* hist_sum = GIc + (size_t)VV * GG;                     // B*128 f32
    float* last_out = hist_sum + (size_t)BB * 128;               // B*64 f32
    int* seqlen = (int*)(last_out + (size_t)BB * 64);            // B int

    prep<<<NBT + BB / 2, 256, 0, stream>>>(emb, Wih, bih, hist_item, hist_cate,
                                           mask, GIi, GIc, hist_sum, seqlen);
    mimn_rnn<<<BB / RPB, 512, 0, stream>>>(hist_item, hist_cate, mask, Wih, Whh, bhh,
                                           Wp, bp, Wo, bo, M0, GIi, GIc, seqlen, last_out);
    final_mlp<<<BB, 128, 0, stream>>>(item, cate, emb, hist_sum, last_out,
                                      fc1w, fc1b, pa1, fc2w, fc2b, pa2, fc3w, fc3b,
                                      (float*)d_out);
}